// Round 1
// baseline (3173.603 us; speedup 1.0000x reference)
//
#include <hip/hip_runtime.h>

// GRU_54614804135975: 128-step GRU (B=1024,D=256,H=1024) + per-frame BatchNorm.
// Strategy: fold inp->gi through W_lin (gi_t = h_t @ (W_lin.T@W_ih.T) + c) so each
// step is ONE bf16-MFMA matmul h_t @ W_big (1024x4096) with gates fused in-register.
// out_t (the returned frames) is off the critical path: computed by 32 extra blocks
// in the NEXT step's launch. BN done in-place in d_out at the end.

#define DEVI __device__ __forceinline__

typedef __bf16 bf16x8 __attribute__((ext_vector_type(8)));
typedef float f32x4 __attribute__((ext_vector_type(4)));

typedef __attribute__((address_space(1))) const unsigned int g_u32;
typedef __attribute__((address_space(3))) unsigned int l_u32;

DEVI unsigned short f2b(float f) {
  union { float f; unsigned u; } v; v.f = f;
  return (unsigned short)((v.u + 0x7fffu + ((v.u >> 16) & 1u)) >> 16);
}

DEVI void gl_lds16(const void* g, void* s) {
  __builtin_amdgcn_global_load_lds((g_u32*)g, (l_u32*)s, 16, 0, 0);
}

DEVI float sigm(float x) { return 1.0f / (1.0f + __expf(-x)); }
DEVI float tanh_f(float x) {
  float t = __expf(-2.0f * fabsf(x));
  float r = (1.0f - t) / (1.0f + t);
  return x >= 0.0f ? r : -r;
}

// ---------------- fused step kernel ----------------
// blocks [0, main_n): compute h_{t+1}[mb*128.., j=nb*32..] from A (bf16, MxK) @ Bw
//   (Bw is n-major [4096][K], cols grouped per 32-j tile as [r|z|i_n|h_n]x32).
// blocks [main_n, ...): out-GEMM  outp = A @ Wout^T(+bout)  (Wout n-major [256][K]).
__global__ __launch_bounds__(256) void stepk(
    const unsigned short* __restrict__ A, int K,
    const unsigned short* __restrict__ Bw,
    const float* __restrict__ cvec,
    const float* __restrict__ hprev,
    float* __restrict__ houtf,
    unsigned short* __restrict__ houtb,
    const unsigned short* __restrict__ Wout,
    const float* __restrict__ bout,
    float* __restrict__ outp,
    int main_n)
{
  __shared__ __align__(16) unsigned short As[128 * 64];
  __shared__ __align__(16) unsigned short Bs[128 * 64];
  const int tid = threadIdx.x;
  const int w = tid >> 6, lane = tid & 63;
  const int srow = lane >> 3;                  // 0..7 row within 8-row staging group
  const int schunk = (lane & 7) ^ srow;        // XOR-swizzled 16B chunk (global side)
  const int l15 = lane & 15, lg = lane >> 4;
  const int iters = K >> 6;

  if ((int)blockIdx.x < main_n) {
    const int mb = blockIdx.x >> 5;
    const int nb = blockIdx.x & 31;
    const int wr = w >> 1, wc = w & 1;
    f32x4 acc[4][4] = {};
    const unsigned short* Ag = A + (size_t)(mb * 128 + w * 32) * K;
    const unsigned short* Bg = Bw + (size_t)(nb * 128 + w * 32) * K;
    for (int kt = 0; kt < iters; ++kt) {
      const int k0 = kt * 64;
      __syncthreads();
#pragma unroll
      for (int q = 0; q < 4; ++q) {
        gl_lds16(Ag + (size_t)(q * 8 + srow) * K + k0 + schunk * 8,
                 (char*)As + (w * 32 + q * 8) * 128);
        gl_lds16(Bg + (size_t)(q * 8 + srow) * K + k0 + schunk * 8,
                 (char*)Bs + (w * 32 + q * 8) * 128);
      }
      __syncthreads();
#pragma unroll
      for (int kk = 0; kk < 2; ++kk) {
        bf16x8 a[4], b[4];
#pragma unroll
        for (int mi = 0; mi < 4; ++mi) {
          int rl = wr * 64 + mi * 16 + l15;
          int slot = (kk * 4 + lg) ^ (rl & 7);
          a[mi] = *(const bf16x8*)(As + rl * 64 + slot * 8);
        }
#pragma unroll
        for (int g = 0; g < 4; ++g) {
          int cl = g * 32 + wc * 16 + l15;
          int slot = (kk * 4 + lg) ^ (cl & 7);
          b[g] = *(const bf16x8*)(Bs + cl * 64 + slot * 8);
        }
#pragma unroll
        for (int mi = 0; mi < 4; ++mi)
#pragma unroll
          for (int g = 0; g < 4; ++g)
            acc[mi][g] = __builtin_amdgcn_mfma_f32_16x16x32_bf16(
                a[mi], b[g], acc[mi][g], 0, 0, 0);
      }
    }
    // gate epilogue: acc[mi][0..3] = r,z,i_n,h_n for the SAME (row, j) per lane
    const int j = nb * 32 + wc * 16 + l15;
    const float cr = cvec[j], cz = cvec[1024 + j], cin = cvec[2048 + j],
                chn = cvec[3072 + j];
#pragma unroll
    for (int mi = 0; mi < 4; ++mi) {
#pragma unroll
      for (int i = 0; i < 4; ++i) {
        int row = mb * 128 + wr * 64 + mi * 16 + lg * 4 + i;
        float rg = sigm(acc[mi][0][i] + cr);
        float zg = sigm(acc[mi][1][i] + cz);
        float ng = tanh_f(acc[mi][2][i] + cin + rg * (acc[mi][3][i] + chn));
        float ho = hprev[(size_t)row * 1024 + j];
        float hnew = (1.0f - zg) * ng + zg * ho;
        houtf[(size_t)row * 1024 + j] = hnew;
        houtb[(size_t)row * 1024 + j] = f2b(hnew);
      }
    }
  } else {
    // ---- out block: 128x64 tile of A @ Wout^T ----
    const int ob = blockIdx.x - main_n;
    const int om = ob >> 2, on = ob & 3;
    const int wr = w & 1, wc = w >> 1;
    f32x4 acc[4][2] = {};
    const unsigned short* Ag = A + (size_t)(om * 128 + w * 32) * K;
    const unsigned short* Bg = Wout + (size_t)(on * 64 + w * 16) * K;
    for (int kt = 0; kt < iters; ++kt) {
      const int k0 = kt * 64;
      __syncthreads();
#pragma unroll
      for (int q = 0; q < 4; ++q)
        gl_lds16(Ag + (size_t)(q * 8 + srow) * K + k0 + schunk * 8,
                 (char*)As + (w * 32 + q * 8) * 128);
#pragma unroll
      for (int q = 0; q < 2; ++q)
        gl_lds16(Bg + (size_t)(q * 8 + srow) * K + k0 + schunk * 8,
                 (char*)Bs + (w * 16 + q * 8) * 128);
      __syncthreads();
#pragma unroll
      for (int kk = 0; kk < 2; ++kk) {
        bf16x8 a[4], b[2];
#pragma unroll
        for (int mi = 0; mi < 4; ++mi) {
          int rl = wr * 64 + mi * 16 + l15;
          int slot = (kk * 4 + lg) ^ (rl & 7);
          a[mi] = *(const bf16x8*)(As + rl * 64 + slot * 8);
        }
#pragma unroll
        for (int ni = 0; ni < 2; ++ni) {
          int cl = wc * 32 + ni * 16 + l15;
          int slot = (kk * 4 + lg) ^ (cl & 7);
          b[ni] = *(const bf16x8*)(Bs + cl * 64 + slot * 8);
        }
#pragma unroll
        for (int mi = 0; mi < 4; ++mi)
#pragma unroll
          for (int ni = 0; ni < 2; ++ni)
            acc[mi][ni] = __builtin_amdgcn_mfma_f32_16x16x32_bf16(
                a[mi], b[ni], acc[mi][ni], 0, 0, 0);
      }
    }
    if (outp != nullptr) {
#pragma unroll
      for (int mi = 0; mi < 4; ++mi)
#pragma unroll
        for (int ni = 0; ni < 2; ++ni) {
          int d = on * 64 + wc * 32 + ni * 16 + l15;
          float bb = bout[d];
#pragma unroll
          for (int i = 0; i < 4; ++i) {
            int row = om * 128 + wr * 64 + mi * 16 + lg * 4 + i;
            outp[(size_t)row * 256 + d] = acc[mi][ni][i] + bb;
          }
        }
    }
  }
}

// ---------------- plain 128x128 GEMM (for W_lin.T @ W_ih.T precompute) ----------
__global__ __launch_bounds__(256) void gemm128(
    const unsigned short* __restrict__ A, const unsigned short* __restrict__ B,
    float* __restrict__ C, int K, int nT)
{
  __shared__ __align__(16) unsigned short As[128 * 64];
  __shared__ __align__(16) unsigned short Bs[128 * 64];
  const int tid = threadIdx.x;
  const int w = tid >> 6, lane = tid & 63;
  const int srow = lane >> 3, schunk = (lane & 7) ^ srow;
  const int l15 = lane & 15, lg = lane >> 4;
  const int mb = blockIdx.x / nT, nb = blockIdx.x % nT;
  const int wr = w >> 1, wc = w & 1;
  const int N = nT * 128;
  f32x4 acc[4][4] = {};
  const unsigned short* Ag = A + (size_t)(mb * 128 + w * 32) * K;
  const unsigned short* Bg = B + (size_t)(nb * 128 + w * 32) * K;
  for (int kt = 0; kt < (K >> 6); ++kt) {
    const int k0 = kt * 64;
    __syncthreads();
#pragma unroll
    for (int q = 0; q < 4; ++q) {
      gl_lds16(Ag + (size_t)(q * 8 + srow) * K + k0 + schunk * 8,
               (char*)As + (w * 32 + q * 8) * 128);
      gl_lds16(Bg + (size_t)(q * 8 + srow) * K + k0 + schunk * 8,
               (char*)Bs + (w * 32 + q * 8) * 128);
    }
    __syncthreads();
#pragma unroll
    for (int kk = 0; kk < 2; ++kk) {
      bf16x8 a[4], b[4];
#pragma unroll
      for (int mi = 0; mi < 4; ++mi) {
        int rl = wr * 64 + mi * 16 + l15;
        int slot = (kk * 4 + lg) ^ (rl & 7);
        a[mi] = *(const bf16x8*)(As + rl * 64 + slot * 8);
      }
#pragma unroll
      for (int g = 0; g < 4; ++g) {
        int cl = g * 32 + wc * 16 + l15;
        int slot = (kk * 4 + lg) ^ (cl & 7);
        b[g] = *(const bf16x8*)(Bs + cl * 64 + slot * 8);
      }
#pragma unroll
      for (int mi = 0; mi < 4; ++mi)
#pragma unroll
        for (int g = 0; g < 4; ++g)
          acc[mi][g] = __builtin_amdgcn_mfma_f32_16x16x32_bf16(
              a[mi], b[g], acc[mi][g], 0, 0, 0);
    }
  }
#pragma unroll
  for (int mi = 0; mi < 4; ++mi)
#pragma unroll
    for (int g = 0; g < 4; ++g)
#pragma unroll
      for (int i = 0; i < 4; ++i)
        C[(size_t)(mb * 128 + wr * 64 + mi * 16 + lg * 4 + i) * N + nb * 128 +
          g * 32 + wc * 16 + l15] = acc[mi][g][i];
}

// ---------------- small prep kernels ----------------
__global__ void castall(const float* __restrict__ x, const float* __restrict__ wih,
                        const float* __restrict__ wlin, unsigned short* __restrict__ xb,
                        unsigned short* __restrict__ wihb, unsigned short* __restrict__ wlb) {
  int i = blockIdx.x * 256 + threadIdx.x;  // grid covers 786432
  if (i < 262144) { xb[i] = f2b(x[i]); wlb[i] = f2b(wlin[i]); }
  if (i < 786432) wihb[i] = f2b(wih[i]);
}

// W_lin (256x1024) -> bf16 transpose (1024x256)
__global__ void tcast(const float* __restrict__ in, unsigned short* __restrict__ out) {
  __shared__ float t[32][33];
  int i0 = blockIdx.x * 32, d0 = blockIdx.y * 32;
  for (int r = threadIdx.y; r < 32; r += 8)
    t[r][threadIdx.x] = in[(size_t)(d0 + r) * 1024 + i0 + threadIdx.x];
  __syncthreads();
  for (int r = threadIdx.y; r < 32; r += 8)
    out[(size_t)(i0 + r) * 256 + d0 + threadIdx.x] = f2b(t[threadIdx.x][r]);
}

// Build W_big (n-major [4096][1024]) from C_MT = (W_lin.T@W_ih.T).T and W_hh
__global__ void asmWp(const float* __restrict__ CMT, const float* __restrict__ Whh,
                      unsigned short* __restrict__ Wp) {
  int col = blockIdx.x;
  int jt = col >> 7, gate = (col >> 5) & 3, c = col & 31;
  int j = jt * 32 + c;
  const float* s1;
  const float* s2 = nullptr;
  if (gate == 0)      { s1 = CMT + (size_t)j * 1024;          s2 = Whh + (size_t)j * 1024; }
  else if (gate == 1) { s1 = CMT + (size_t)(1024 + j) * 1024; s2 = Whh + (size_t)(1024 + j) * 1024; }
  else if (gate == 2) { s1 = CMT + (size_t)(2048 + j) * 1024; }
  else                { s1 = Whh + (size_t)(2048 + j) * 1024; }
  unsigned short* dst = Wp + (size_t)col * 1024;
  for (int k = threadIdx.x; k < 1024; k += 256) {
    float v = s1[k] + (s2 ? s2[k] : 0.0f);
    dst[k] = f2b(v);
  }
}

// Step-0 weights: permuted W_ih.T (n-major [4096][256]), h_n group = 0
__global__ void asmWp0(const float* __restrict__ Wih, unsigned short* __restrict__ Wp0) {
  int col = blockIdx.x;
  int jt = col >> 7, gate = (col >> 5) & 3, c = col & 31;
  int j = jt * 32 + c;
  int d = threadIdx.x;  // 256
  float v = 0.0f;
  if (gate < 3) v = Wih[(size_t)(gate * 1024 + j) * 256 + d];
  Wp0[(size_t)col * 256 + d] = f2b(v);
}

__global__ void biask(const float* __restrict__ Wih, const float* __restrict__ bih,
                      const float* __restrict__ bhh, const float* __restrict__ blin,
                      float* __restrict__ cbig, float* __restrict__ c0) {
  int j = blockIdx.x * 256 + threadIdx.x;
  if (j >= 1024) return;
  float bli[3];
  for (int g = 0; g < 3; ++g) {
    int gg = g * 1024 + j;
    float s = bih[gg];
    const float* wrow = Wih + (size_t)gg * 256;
    for (int d = 0; d < 256; ++d) s += blin[d] * wrow[d];
    bli[g] = s;
  }
  cbig[j] = bli[0] + bhh[j];
  cbig[1024 + j] = bli[1] + bhh[1024 + j];
  cbig[2048 + j] = bli[2];
  cbig[3072 + j] = bhh[2048 + j];
  c0[j] = bih[j] + bhh[j];
  c0[1024 + j] = bih[1024 + j] + bhh[1024 + j];
  c0[2048 + j] = bih[2048 + j];
  c0[3072 + j] = bhh[2048 + j];
}

// ---------------- BatchNorm ----------------
__global__ void bnstats(const float* __restrict__ o, float* __restrict__ mean,
                        float* __restrict__ rstd) {
  int t = blockIdx.x;
  int d = threadIdx.x & 255;
  int bq = threadIdx.x >> 8;  // 0..3
  const float* base = o + (size_t)t * 1024 * 256;
  float s = 0.0f, ss = 0.0f;
  for (int b = bq * 256; b < bq * 256 + 256; ++b) {
    float v = base[(size_t)b * 256 + d];
    s += v; ss += v * v;
  }
  __shared__ float S[4][256], SS[4][256];
  S[bq][d] = s; SS[bq][d] = ss;
  __syncthreads();
  if (threadIdx.x < 256) {
    float st = S[0][d] + S[1][d] + S[2][d] + S[3][d];
    float sst = SS[0][d] + SS[1][d] + SS[2][d] + SS[3][d];
    float m = st * (1.0f / 1024.0f);
    float var = sst * (1.0f / 1024.0f) - m * m;
    mean[t * 256 + d] = m;
    rstd[t * 256 + d] = rsqrtf(var + 1e-5f);
  }
}

__global__ void bnnorm(float* __restrict__ o, const float* __restrict__ mean,
                       const float* __restrict__ rstd) {
  size_t base = ((size_t)blockIdx.x * 256 + threadIdx.x) * 4;  // exact: 32768*256*4
  int t = (int)(base >> 18);
  int d = (int)(base & 255);
  float4 v = *(float4*)(o + base);
  const float* mp = mean + t * 256 + d;
  const float* rp = rstd + t * 256 + d;
  float4 r;
  r.x = (v.x - mp[0]) * rp[0];
  r.y = (v.y - mp[1]) * rp[1];
  r.z = (v.z - mp[2]) * rp[2];
  r.w = (v.w - mp[3]) * rp[3];
  *(float4*)(o + base) = r;
}

// ---------------- launch ----------------
extern "C" void kernel_launch(void* const* d_in, const int* in_sizes, int n_in,
                              void* d_out, int out_size, void* d_ws, size_t ws_size,
                              hipStream_t stream) {
  (void)in_sizes; (void)n_in; (void)out_size; (void)ws_size;
  const float* x    = (const float*)d_in[0];
  const float* h0   = (const float*)d_in[1];
  const float* Wih  = (const float*)d_in[2];
  const float* Whh  = (const float*)d_in[3];
  const float* bih  = (const float*)d_in[4];
  const float* bhh  = (const float*)d_in[5];
  const float* Wlin = (const float*)d_in[6];
  const float* blin = (const float*)d_in[7];
  float* out = (float*)d_out;

  char* ws = (char*)d_ws;
  size_t off = 0;
  auto alloc = [&](size_t bytes) {
    char* p = ws + off;
    off += (bytes + 255) & ~(size_t)255;
    return p;
  };
  unsigned short* WP   = (unsigned short*)alloc(4096ull * 1024 * 2);
  unsigned short* WP0  = (unsigned short*)alloc(4096ull * 256 * 2);
  unsigned short* WIHB = (unsigned short*)alloc(3072ull * 256 * 2);
  unsigned short* WLT  = (unsigned short*)alloc(1024ull * 256 * 2);
  unsigned short* WLB  = (unsigned short*)alloc(256ull * 1024 * 2);
  unsigned short* XB   = (unsigned short*)alloc(1024ull * 256 * 2);
  float* CMT  = (float*)alloc(3072ull * 1024 * 4);
  float* CBIG = (float*)alloc(4096 * 4);
  float* C0   = (float*)alloc(4096 * 4);
  float* HF0  = (float*)alloc(1024ull * 1024 * 4);
  float* HF1  = (float*)alloc(1024ull * 1024 * 4);
  unsigned short* HB0 = (unsigned short*)alloc(1024ull * 1024 * 2);
  unsigned short* HB1 = (unsigned short*)alloc(1024ull * 1024 * 2);
  float* MEAN = (float*)alloc(128 * 256 * 4);
  float* RSTD = (float*)alloc(128 * 256 * 4);
  float* HF[2] = {HF0, HF1};
  unsigned short* HB[2] = {HB0, HB1};

  // precompute: casts, W_lin transpose, C_MT = W_ih @ W_lin, fused weights, biases
  castall<<<3072, 256, 0, stream>>>(x, Wih, Wlin, XB, WIHB, WLB);
  tcast<<<dim3(32, 8), dim3(32, 8), 0, stream>>>(Wlin, WLT);
  gemm128<<<192, 256, 0, stream>>>(WIHB, WLT, CMT, 256, 8);
  asmWp<<<4096, 256, 0, stream>>>(CMT, Whh, WP);
  asmWp0<<<4096, 256, 0, stream>>>(Wih, WP0);
  biask<<<4, 256, 0, stream>>>(Wih, bih, bhh, blin, CBIG, C0);

  // step 0: h_1 = gates(x @ W_ih.T + b_ih, b_hh, h0)
  stepk<<<256, 256, 0, stream>>>(XB, 256, WP0, C0, h0, HF[1], HB[1],
                                 nullptr, nullptr, nullptr, 256);
  // steps 1..127: h_{t+1} = gates(h_t @ W_big + c); fused out_{t-1} = h_t @ W_lin.T
  for (int t = 1; t <= 127; ++t) {
    stepk<<<288, 256, 0, stream>>>(HB[t & 1], 1024, WP, CBIG, HF[t & 1],
                                   HF[(t + 1) & 1], HB[(t + 1) & 1],
                                   WLB, blin, out + (size_t)(t - 1) * 262144, 256);
  }
  // final frame: out_127 = h_128 @ W_lin.T
  stepk<<<32, 256, 0, stream>>>(HB[0], 1024, WP, CBIG, nullptr, nullptr, nullptr,
                                WLB, blin, out + 127ull * 262144, 0);

  // BatchNorm1d (training stats), in-place on d_out
  bnstats<<<128, 1024, 0, stream>>>(out, MEAN, RSTD);
  bnnorm<<<32768, 256, 0, stream>>>(out, MEAN, RSTD);
}